// Round 3
// baseline (472.626 us; speedup 1.0000x reference)
//
#include <hip/hip_runtime.h>
#include <hip/hip_bf16.h>
#include <cstdint>

#define INCH 128
#define NHID 256
#define OUTCH 128

// ---------------- threefry2x32 (JAX-compatible) ----------------
__device__ __forceinline__ unsigned rotl32(unsigned x, int d) {
    return (x << d) | (x >> (32 - d));
}

__device__ __forceinline__ void threefry2x32(unsigned k0, unsigned k1,
                                             unsigned x0, unsigned x1,
                                             unsigned& o0, unsigned& o1) {
    unsigned ks2 = k0 ^ k1 ^ 0x1BD11BDAu;
#define TF_R(r) { x0 += x1; x1 = rotl32(x1, (r)); x1 ^= x0; }
    x0 += k0; x1 += k1;
    TF_R(13) TF_R(15) TF_R(26) TF_R(6)
    x0 += k1; x1 += ks2 + 1u;
    TF_R(17) TF_R(29) TF_R(16) TF_R(24)
    x0 += ks2; x1 += k0 + 2u;
    TF_R(13) TF_R(15) TF_R(26) TF_R(6)
    x0 += k0; x1 += k1 + 3u;
    TF_R(17) TF_R(29) TF_R(16) TF_R(24)
    x0 += k1; x1 += ks2 + 4u;
    TF_R(13) TF_R(15) TF_R(26) TF_R(6)
    x0 += ks2; x1 += k0 + 5u;
#undef TF_R
    o0 = x0; o1 = x1;
}

// JAX partitionable threefry, 32-bit draw: counter = flat index j (hi=0, lo=j),
// key = (0, 42); bits = o0 ^ o1. uniform<0.5  <=>  MSB(bits)==0.
__device__ __forceinline__ bool dropout_keep(unsigned j) {
    unsigned o0, o1;
    threefry2x32(0u, 42u, 0u, j, o0, o1);
    return ((o0 ^ o1) & 0x80000000u) == 0u;
}

// ---------------- graph preprocessing ----------------
__global__ void k_init(float* deg, int* cnt, int N) {
    int i = blockIdx.x * blockDim.x + threadIdx.x;
    if (i < N) { deg[i] = 1.0f; cnt[i] = 0; }  // self-loop weight 1
}

__global__ void k_edge_deg_hist(const int* __restrict__ dst, const float* __restrict__ w,
                                float* deg, int* cnt, int E) {
    int e = blockIdx.x * blockDim.x + threadIdx.x;
    if (e < E) {
        int d = dst[e];
        atomicAdd(&deg[d], w[e]);
        atomicAdd(&cnt[d], 1);
    }
}

__global__ void k_dinv(float* deg, int N) {
    int i = blockIdx.x * blockDim.x + threadIdx.x;
    if (i < N) {
        float dg = deg[i];
        deg[i] = (dg > 0.f) ? rsqrtf(dg) : 0.f;
    }
}

__global__ void scan_block(const int* __restrict__ cnt, int* __restrict__ rowptr,
                           int* __restrict__ bsum, int N) {
    __shared__ int s[256];
    int t = threadIdx.x;
    int i = blockIdx.x * 256 + t;
    int v = (i < N) ? cnt[i] : 0;
    s[t] = v;
    __syncthreads();
    for (int off = 1; off < 256; off <<= 1) {
        int tv = (t >= off) ? s[t - off] : 0;
        __syncthreads();
        s[t] += tv;
        __syncthreads();
    }
    if (i < N) rowptr[i] = s[t] - v;          // exclusive within block
    if (t == 255) bsum[blockIdx.x] = s[255];  // block total
}

__global__ void scan_partials(int* bsum, int nb) {
    __shared__ int s[256];
    int t = threadIdx.x;
    int v = (t < nb) ? bsum[t] : 0;
    s[t] = v;
    __syncthreads();
    for (int off = 1; off < 256; off <<= 1) {
        int tv = (t >= off) ? s[t - off] : 0;
        __syncthreads();
        s[t] += tv;
        __syncthreads();
    }
    if (t < nb) bsum[t] = s[t] - v;  // exclusive
}

__global__ void scan_add(int* rowptr, int* cursor, const int* __restrict__ bsum,
                         int N, int E) {
    int i = blockIdx.x * 256 + threadIdx.x;
    if (i < N) {
        int r = rowptr[i] + bsum[blockIdx.x];
        rowptr[i] = r;
        cursor[i] = r;
    }
    if (i == N) rowptr[N] = E;
}

__global__ void k_place(const int* __restrict__ src, const int* __restrict__ dst,
                        const float* __restrict__ w, const float* __restrict__ dinv,
                        int* cursor, int* __restrict__ col, float* __restrict__ val, int E) {
    int e = blockIdx.x * blockDim.x + threadIdx.x;
    if (e < E) {
        int s = src[e], d = dst[e];
        float nrm = dinv[s] * w[e] * dinv[d];
        int pos = atomicAdd(&cursor[d], 1);
        col[pos] = s;
        val[pos] = nrm;
    }
}

// ---------------- fp32 SGEMM v2: C[M,N] = A[M,K] @ B[K,N] (+bias,+relu+dropout) ----
// BN = 128 fixed. BM in {128, 64}. 256 threads: tx = tid&15 (cols), ty = tid>>4.
// Thread tile: TM x 8, cols split-halves {tx*4, 64+tx*4}, rows split into
// ROW_GROUPS groups of 4 at {g*64 + ty*4}. As stored k-major [16][BM] so
// fragment reads are ds_read_b128 with <=2-way bank aliasing (free).
template <int BM, bool ACT>
__global__ __launch_bounds__(256) void sgemm_v2(const float* __restrict__ A,
                                                const float* __restrict__ B,
                                                const float* __restrict__ bias,
                                                float* __restrict__ C,
                                                int M, int N, int K) {
    constexpr int TM = BM / 16;        // 8 or 4
    constexpr int RG = TM / 4;         // 2 or 1 row groups
    __shared__ float As[16][BM];       // [k][row]
    __shared__ float Bs[16][128];      // [k][col]
    const int col0 = blockIdx.x * 128;
    const int row0 = blockIdx.y * BM;
    const int tid = threadIdx.x;
    const int tx = tid & 15, ty = tid >> 4;

    float acc[TM][8] = {};

    for (int k0 = 0; k0 < K; k0 += 16) {
        // stage A tile (transpose to k-major): BM*16 floats = BM*4 float4s
#pragma unroll
        for (int q = tid; q < BM * 4; q += 256) {
            int r = q >> 2;
            int kk = (q & 3) << 2;
            int gr = row0 + r;
            float4 a = make_float4(0.f, 0.f, 0.f, 0.f);
            if (gr < M) a = *reinterpret_cast<const float4*>(&A[(size_t)gr * K + k0 + kk]);
            As[kk + 0][r] = a.x; As[kk + 1][r] = a.y;
            As[kk + 2][r] = a.z; As[kk + 3][r] = a.w;
        }
        // stage B tile: 16 x 128 floats = 512 float4s
#pragma unroll
        for (int q = tid; q < 512; q += 256) {
            int r = q >> 5;
            int cc = (q & 31) << 2;
            float4 b = *reinterpret_cast<const float4*>(&B[(size_t)(k0 + r) * N + col0 + cc]);
            *reinterpret_cast<float4*>(&Bs[r][cc]) = b;
        }
        __syncthreads();
#pragma unroll
        for (int k = 0; k < 16; ++k) {
            const float4* As4 = reinterpret_cast<const float4*>(&As[k][0]);
            const float4* Bs4 = reinterpret_cast<const float4*>(&Bs[k][0]);
            float4 af[RG];
#pragma unroll
            for (int g = 0; g < RG; ++g) af[g] = As4[g * 16 + ty];
            float4 bf[2];
            bf[0] = Bs4[tx];
            bf[1] = Bs4[16 + tx];
#pragma unroll
            for (int g = 0; g < RG; ++g) {
                const float a0 = af[g].x, a1 = af[g].y, a2 = af[g].z, a3 = af[g].w;
#pragma unroll
                for (int h = 0; h < 2; ++h) {
                    const float4 b = bf[h];
                    float* ac0 = &acc[g * 4 + 0][h * 4];
                    float* ac1 = &acc[g * 4 + 1][h * 4];
                    float* ac2 = &acc[g * 4 + 2][h * 4];
                    float* ac3 = &acc[g * 4 + 3][h * 4];
                    ac0[0] = fmaf(a0, b.x, ac0[0]); ac0[1] = fmaf(a0, b.y, ac0[1]);
                    ac0[2] = fmaf(a0, b.z, ac0[2]); ac0[3] = fmaf(a0, b.w, ac0[3]);
                    ac1[0] = fmaf(a1, b.x, ac1[0]); ac1[1] = fmaf(a1, b.y, ac1[1]);
                    ac1[2] = fmaf(a1, b.z, ac1[2]); ac1[3] = fmaf(a1, b.w, ac1[3]);
                    ac2[0] = fmaf(a2, b.x, ac2[0]); ac2[1] = fmaf(a2, b.y, ac2[1]);
                    ac2[2] = fmaf(a2, b.z, ac2[2]); ac2[3] = fmaf(a2, b.w, ac2[3]);
                    ac3[0] = fmaf(a3, b.x, ac3[0]); ac3[1] = fmaf(a3, b.y, ac3[1]);
                    ac3[2] = fmaf(a3, b.z, ac3[2]); ac3[3] = fmaf(a3, b.w, ac3[3]);
                }
            }
        }
        __syncthreads();
    }

    // epilogue
#pragma unroll
    for (int g = 0; g < RG; ++g) {
#pragma unroll
        for (int i = 0; i < 4; ++i) {
            int gr = row0 + g * 64 + ty * 4 + i;
            if (gr >= M) continue;
#pragma unroll
            for (int h = 0; h < 2; ++h) {
                int gc = col0 + h * 64 + tx * 4;
                float4 o = make_float4(acc[g * 4 + i][h * 4 + 0], acc[g * 4 + i][h * 4 + 1],
                                       acc[g * 4 + i][h * 4 + 2], acc[g * 4 + i][h * 4 + 3]);
                if (ACT) {
                    o.x = fmaxf(o.x + bias[gc + 0], 0.f);
                    o.y = fmaxf(o.y + bias[gc + 1], 0.f);
                    o.z = fmaxf(o.z + bias[gc + 2], 0.f);
                    o.w = fmaxf(o.w + bias[gc + 3], 0.f);
                    unsigned j = (unsigned)gr * (unsigned)N + (unsigned)gc;
                    o.x = dropout_keep(j + 0u) ? o.x * 2.f : 0.f;
                    o.y = dropout_keep(j + 1u) ? o.y * 2.f : 0.f;
                    o.z = dropout_keep(j + 2u) ? o.z * 2.f : 0.f;
                    o.w = dropout_keep(j + 3u) ? o.w * 2.f : 0.f;
                }
                *reinterpret_cast<float4*>(&C[(size_t)gr * N + gc]) = o;
            }
        }
    }
}

// ------------- CSR gather aggregation, F=128, float4 lanes -------------------
// out[n] = bias + dinv[n]^2 * h[n] + sum_{p in row n} val[p] * h[col[p]]
// 32 lanes per node (float4 each), 8 nodes per 256-thread block.
__global__ __launch_bounds__(256) void k_aggregate4(const float4* __restrict__ h4,
                                                    const float* __restrict__ dinv,
                                                    const int* __restrict__ rowptr,
                                                    const int* __restrict__ col,
                                                    const float* __restrict__ val,
                                                    const float* __restrict__ bias,  // may be null
                                                    float4* __restrict__ out4, int N) {
    int node = blockIdx.x * 8 + (threadIdx.x >> 5);
    int lane = threadIdx.x & 31;
    if (node >= N) return;
    float di = dinv[node];
    float s = di * di;
    float4 self = h4[(size_t)node * 32 + lane];
    float4 acc;
    acc.x = self.x * s; acc.y = self.y * s; acc.z = self.z * s; acc.w = self.w * s;
    if (bias) {
        float4 b = reinterpret_cast<const float4*>(bias)[lane];
        acc.x += b.x; acc.y += b.y; acc.z += b.z; acc.w += b.w;
    }
    int p0 = rowptr[node], p1 = rowptr[node + 1];
    int p = p0;
    for (; p + 4 <= p1; p += 4) {
        int c0 = col[p], c1 = col[p + 1], c2 = col[p + 2], c3 = col[p + 3];
        float v0 = val[p], v1 = val[p + 1], v2 = val[p + 2], v3 = val[p + 3];
        float4 g0 = h4[(size_t)c0 * 32 + lane];
        float4 g1 = h4[(size_t)c1 * 32 + lane];
        float4 g2 = h4[(size_t)c2 * 32 + lane];
        float4 g3 = h4[(size_t)c3 * 32 + lane];
        acc.x = fmaf(g0.x, v0, acc.x); acc.y = fmaf(g0.y, v0, acc.y);
        acc.z = fmaf(g0.z, v0, acc.z); acc.w = fmaf(g0.w, v0, acc.w);
        acc.x = fmaf(g1.x, v1, acc.x); acc.y = fmaf(g1.y, v1, acc.y);
        acc.z = fmaf(g1.z, v1, acc.z); acc.w = fmaf(g1.w, v1, acc.w);
        acc.x = fmaf(g2.x, v2, acc.x); acc.y = fmaf(g2.y, v2, acc.y);
        acc.z = fmaf(g2.z, v2, acc.z); acc.w = fmaf(g2.w, v2, acc.w);
        acc.x = fmaf(g3.x, v3, acc.x); acc.y = fmaf(g3.y, v3, acc.y);
        acc.z = fmaf(g3.z, v3, acc.z); acc.w = fmaf(g3.w, v3, acc.w);
    }
    for (; p < p1; ++p) {
        int c = col[p];
        float v = val[p];
        float4 g = h4[(size_t)c * 32 + lane];
        acc.x = fmaf(g.x, v, acc.x); acc.y = fmaf(g.y, v, acc.y);
        acc.z = fmaf(g.z, v, acc.z); acc.w = fmaf(g.w, v, acc.w);
    }
    out4[(size_t)node * 32 + lane] = acc;
}

// ---------------- launch ----------------
extern "C" void kernel_launch(void* const* d_in, const int* in_sizes, int n_in,
                              void* d_out, int out_size, void* d_ws, size_t ws_size,
                              hipStream_t stream) {
    (void)n_in; (void)out_size; (void)ws_size;
    const float* x  = (const float*)d_in[0];
    const int*   ei = (const int*)d_in[1];
    const float* w  = (const float*)d_in[2];
    const float* W1 = (const float*)d_in[3];
    const float* b1 = (const float*)d_in[4];
    const float* W2 = (const float*)d_in[5];
    const float* b2 = (const float*)d_in[6];
    float* out = (float*)d_out;

    int N = in_sizes[0] / INCH;  // 50000
    int E = in_sizes[1] / 2;     // 800000
    const int* src = ei;
    const int* dst = ei + E;

    char* ws = (char*)d_ws;
    size_t off = 0;
    auto alloc = [&](size_t bytes) -> char* {
        size_t p = (off + 255) & ~(size_t)255;
        off = p + bytes;
        return ws + p;
    };
    float* dinv   = (float*)alloc((size_t)N * 4);            // deg -> dinv in place
    int*   cnt    = (int*)  alloc((size_t)N * 4);            // histogram, then cursor
    int*   rowptr = (int*)  alloc((size_t)(N + 1) * 4);
    int*   bsum   = (int*)  alloc(1024);
    int*   col    = (int*)  alloc((size_t)E * 4);
    float* val    = (float*)alloc((size_t)E * 4);
    float* ax     = (float*)alloc((size_t)N * INCH * 4);     // A@x           (N x 128)
    float* hd     = (float*)alloc((size_t)N * NHID * 4);     // relu/dropout  (N x 256)
    float* g2     = (float*)alloc((size_t)N * OUTCH * 4);    // hd @ W2       (N x 128)

    int nb = (N + 255) / 256;
    int eb = (E + 255) / 256;

    k_init<<<nb, 256, 0, stream>>>(dinv, cnt, N);
    k_edge_deg_hist<<<eb, 256, 0, stream>>>(dst, w, dinv, cnt, E);
    k_dinv<<<nb, 256, 0, stream>>>(dinv, N);
    scan_block<<<nb, 256, 0, stream>>>(cnt, rowptr, bsum, N);
    scan_partials<<<1, 256, 0, stream>>>(bsum, nb);
    scan_add<<<nb, 256, 0, stream>>>(rowptr, cnt /*cursor*/, bsum, N, E);
    k_place<<<eb, 256, 0, stream>>>(src, dst, w, dinv, cnt, col, val, E);

    int ab = (N + 7) / 8;  // 8 nodes per block

    // layer 1: ax = A @ x (F=128); hd = dropout(relu(ax @ W1 + b1))
    k_aggregate4<<<ab, 256, 0, stream>>>((const float4*)x, dinv, rowptr, col, val,
                                         nullptr, (float4*)ax, N);
    dim3 gg1(NHID / 128, (N + 127) / 128);
    sgemm_v2<128, true><<<gg1, 256, 0, stream>>>(ax, W1, b1, hd, N, NHID, INCH);

    // layer 2: g2 = hd @ W2 ; out = A @ g2 + b2 (F=128)
    dim3 gg2(OUTCH / 128, (N + 63) / 64);
    sgemm_v2<64, false><<<gg2, 256, 0, stream>>>(hd, W2, nullptr, g2, N, OUTCH, NHID);
    k_aggregate4<<<ab, 256, 0, stream>>>((const float4*)g2, dinv, rowptr, col, val,
                                         b2, (float4*)out, N);
}

// Round 4
// 422.251 us; speedup vs baseline: 1.1193x; 1.1193x over previous
//
#include <hip/hip_runtime.h>
#include <hip/hip_bf16.h>
#include <cstdint>

#define INCH 128
#define NHID 256
#define OUTCH 128

typedef unsigned short u16;
typedef __attribute__((ext_vector_type(8))) short s8v;   // 8 bf16 (4 VGPRs)
typedef __attribute__((ext_vector_type(4))) float f4v;   // 4 fp32 acc

// ---------------- bf16 hi/lo split (Markidis) ----------------
__device__ __forceinline__ void bsplit(float a, u16& hi, u16& lo) {
    unsigned u = __float_as_uint(a);
    unsigned r = (u + 0x7fffu + ((u >> 16) & 1u)) >> 16;   // RTN-even bf16
    hi = (u16)r;
    float res = a - __uint_as_float(r << 16);
    unsigned u2 = __float_as_uint(res);
    lo = (u16)((u2 + 0x7fffu + ((u2 >> 16) & 1u)) >> 16);
}

// ---------------- threefry2x32 (JAX-compatible) ----------------
__device__ __forceinline__ unsigned rotl32(unsigned x, int d) {
    return (x << d) | (x >> (32 - d));
}

__device__ __forceinline__ void threefry2x32(unsigned k0, unsigned k1,
                                             unsigned x0, unsigned x1,
                                             unsigned& o0, unsigned& o1) {
    unsigned ks2 = k0 ^ k1 ^ 0x1BD11BDAu;
#define TF_R(r) { x0 += x1; x1 = rotl32(x1, (r)); x1 ^= x0; }
    x0 += k0; x1 += k1;
    TF_R(13) TF_R(15) TF_R(26) TF_R(6)
    x0 += k1; x1 += ks2 + 1u;
    TF_R(17) TF_R(29) TF_R(16) TF_R(24)
    x0 += ks2; x1 += k0 + 2u;
    TF_R(13) TF_R(15) TF_R(26) TF_R(6)
    x0 += k0; x1 += k1 + 3u;
    TF_R(17) TF_R(29) TF_R(16) TF_R(24)
    x0 += k1; x1 += ks2 + 4u;
    TF_R(13) TF_R(15) TF_R(26) TF_R(6)
    x0 += ks2; x1 += k0 + 5u;
#undef TF_R
    o0 = x0; o1 = x1;
}

__device__ __forceinline__ bool dropout_keep(unsigned j) {
    unsigned o0, o1;
    threefry2x32(0u, 42u, 0u, j, o0, o1);
    return ((o0 ^ o1) & 0x80000000u) == 0u;
}

// ---------------- graph preprocessing ----------------
__global__ void k_init(float* deg, int* cnt, int N) {
    int i = blockIdx.x * blockDim.x + threadIdx.x;
    if (i < N) { deg[i] = 1.0f; cnt[i] = 0; }  // self-loop weight 1
}

__global__ void k_edge_deg_hist(const int* __restrict__ dst, const float* __restrict__ w,
                                float* deg, int* cnt, int E) {
    int e = blockIdx.x * blockDim.x + threadIdx.x;
    if (e < E) {
        int d = dst[e];
        atomicAdd(&deg[d], w[e]);
        atomicAdd(&cnt[d], 1);
    }
}

__global__ void k_dinv(float* deg, int N) {
    int i = blockIdx.x * blockDim.x + threadIdx.x;
    if (i < N) {
        float dg = deg[i];
        deg[i] = (dg > 0.f) ? rsqrtf(dg) : 0.f;
    }
}

__global__ void scan_block(const int* __restrict__ cnt, int* __restrict__ rowptr,
                           int* __restrict__ bsum, int N) {
    __shared__ int s[256];
    int t = threadIdx.x;
    int i = blockIdx.x * 256 + t;
    int v = (i < N) ? cnt[i] : 0;
    s[t] = v;
    __syncthreads();
    for (int off = 1; off < 256; off <<= 1) {
        int tv = (t >= off) ? s[t - off] : 0;
        __syncthreads();
        s[t] += tv;
        __syncthreads();
    }
    if (i < N) rowptr[i] = s[t] - v;
    if (t == 255) bsum[blockIdx.x] = s[255];
}

__global__ void scan_partials(int* bsum, int nb) {
    __shared__ int s[256];
    int t = threadIdx.x;
    int v = (t < nb) ? bsum[t] : 0;
    s[t] = v;
    __syncthreads();
    for (int off = 1; off < 256; off <<= 1) {
        int tv = (t >= off) ? s[t - off] : 0;
        __syncthreads();
        s[t] += tv;
        __syncthreads();
    }
    if (t < nb) bsum[t] = s[t] - v;
}

__global__ void scan_add(int* rowptr, int* cursor, const int* __restrict__ bsum,
                         int N, int E) {
    int i = blockIdx.x * 256 + threadIdx.x;
    if (i < N) {
        int r = rowptr[i] + bsum[blockIdx.x];
        rowptr[i] = r;
        cursor[i] = r;
    }
    if (i == N) rowptr[N] = E;
}

__global__ void k_place(const int* __restrict__ src, const int* __restrict__ dst,
                        const float* __restrict__ w, const float* __restrict__ dinv,
                        int* cursor, int* __restrict__ col, float* __restrict__ val, int E) {
    int e = blockIdx.x * blockDim.x + threadIdx.x;
    if (e < E) {
        int s = src[e], d = dst[e];
        float nrm = dinv[s] * w[e] * dinv[d];
        int pos = atomicAdd(&cursor[d], 1);
        col[pos] = s;
        val[pos] = nrm;
    }
}

// --------- weight transpose + split: W[K][N] fp32 -> Wh/Wl[N][K] bf16 bits -----
__global__ void conv_wt(const float* __restrict__ W, u16* __restrict__ Wh,
                        u16* __restrict__ Wl, int K, int N) {
    int i = blockIdx.x * 256 + threadIdx.x;
    if (i >= K * N) return;
    int k = i / N, n = i % N;
    u16 hi, lo;
    bsplit(W[i], hi, lo);
    Wh[(size_t)n * K + k] = hi;
    Wl[(size_t)n * K + k] = lo;
}

// ---------------- MFMA split-bf16 GEMM ----------------
// C[M,Ntot] = A[M,K] @ B^T[Ntot,K], A/B given as bf16 hi/lo planes.
// BM=128 rows, BN cols per block; 4 waves as 2x2 of (64 x WN) wave tiles.
// mfma_f32_16x16x32_bf16: A/B-frag lane l: (m|n)=l&15, k=(l>>4)*8+i;
// D: col=l&15, row=(l>>4)*4+reg  [m89/m91 verified].
// ACT: C = dropout(relu(C + bias)) -> hi/lo planes; else fp32 out (no bias).
template <int BN, int WN, bool ACT>
__global__ __launch_bounds__(256) void gemm_mfma(
    const u16* __restrict__ Ah, const u16* __restrict__ Al,
    const u16* __restrict__ Bh, const u16* __restrict__ Bl,
    const float* __restrict__ bias,
    u16* __restrict__ Ch, u16* __restrict__ Cl, float* __restrict__ Cf,
    int M, int Ntot, int K) {
    constexpr int BM = 128;
    constexpr int MFRAG = 4;
    constexpr int NFRAG = WN / 16;
    // rows padded to 40 u16 (80 B = 20-bank stride -> 2-way aliasing, free)
    __shared__ u16 Alh[BM][40], All[BM][40];
    __shared__ u16 Blh[BN][40], Bll[BN][40];

    const int tid = threadIdx.x;
    const int lane = tid & 63;
    const int w = tid >> 6;
    const int wm = (w >> 1) * 64;
    const int wn = (w & 1) * WN;
    const int l15 = lane & 15;
    const int kh = lane >> 4;            // 0..3
    const int row0 = blockIdx.y * BM;
    const int col0 = blockIdx.x * BN;

    f4v acc[MFRAG][NFRAG];
#pragma unroll
    for (int f = 0; f < MFRAG; ++f)
#pragma unroll
        for (int g = 0; g < NFRAG; ++g) acc[f][g] = (f4v){0.f, 0.f, 0.f, 0.f};

    for (int k0 = 0; k0 < K; k0 += 32) {
        // stage A tile: 128 rows x 32 k, both planes, 16B chunks
#pragma unroll
        for (int c = tid; c < BM * 4; c += 256) {
            int m = c >> 2, ko = (c & 3) * 8;
            int gm = row0 + m;
            uint4 vh = make_uint4(0, 0, 0, 0), vl = make_uint4(0, 0, 0, 0);
            if (gm < M) {
                size_t gi = (size_t)gm * K + k0 + ko;
                vh = *reinterpret_cast<const uint4*>(&Ah[gi]);
                vl = *reinterpret_cast<const uint4*>(&Al[gi]);
            }
            *reinterpret_cast<uint4*>(&Alh[m][ko]) = vh;
            *reinterpret_cast<uint4*>(&All[m][ko]) = vl;
        }
        // stage B tile: BN rows x 32 k
#pragma unroll
        for (int c = tid; c < BN * 4; c += 256) {
            int n = c >> 2, ko = (c & 3) * 8;
            size_t gi = (size_t)(col0 + n) * K + k0 + ko;
            *reinterpret_cast<uint4*>(&Blh[n][ko]) = *reinterpret_cast<const uint4*>(&Bh[gi]);
            *reinterpret_cast<uint4*>(&Bll[n][ko]) = *reinterpret_cast<const uint4*>(&Bl[gi]);
        }
        __syncthreads();

        s8v afh[MFRAG], afl[MFRAG], bfh[NFRAG], bfl[NFRAG];
#pragma unroll
        for (int f = 0; f < MFRAG; ++f) {
            afh[f] = *reinterpret_cast<const s8v*>(&Alh[wm + f * 16 + l15][kh * 8]);
            afl[f] = *reinterpret_cast<const s8v*>(&All[wm + f * 16 + l15][kh * 8]);
        }
#pragma unroll
        for (int g = 0; g < NFRAG; ++g) {
            bfh[g] = *reinterpret_cast<const s8v*>(&Blh[wn + g * 16 + l15][kh * 8]);
            bfl[g] = *reinterpret_cast<const s8v*>(&Bll[wn + g * 16 + l15][kh * 8]);
        }
#pragma unroll
        for (int f = 0; f < MFRAG; ++f)
#pragma unroll
            for (int g = 0; g < NFRAG; ++g) {
                acc[f][g] = __builtin_amdgcn_mfma_f32_16x16x32_bf16(afl[f], bfh[g], acc[f][g], 0, 0, 0);
                acc[f][g] = __builtin_amdgcn_mfma_f32_16x16x32_bf16(afh[f], bfl[g], acc[f][g], 0, 0, 0);
                acc[f][g] = __builtin_amdgcn_mfma_f32_16x16x32_bf16(afh[f], bfh[g], acc[f][g], 0, 0, 0);
            }
        __syncthreads();
    }

    // epilogue
#pragma unroll
    for (int f = 0; f < MFRAG; ++f) {
#pragma unroll
        for (int g = 0; g < NFRAG; ++g) {
#pragma unroll
            for (int r = 0; r < 4; ++r) {
                int gr = row0 + wm + f * 16 + kh * 4 + r;
                if (gr >= M) continue;
                int gc = col0 + wn + g * 16 + l15;
                float v = acc[f][g][r];
                if (ACT) {
                    v = fmaxf(v + bias[gc], 0.f);
                    unsigned j = (unsigned)gr * (unsigned)Ntot + (unsigned)gc;
                    v = dropout_keep(j) ? v * 2.f : 0.f;
                    u16 hi, lo;
                    bsplit(v, hi, lo);
                    Ch[(size_t)gr * Ntot + gc] = hi;
                    Cl[(size_t)gr * Ntot + gc] = lo;
                } else {
                    Cf[(size_t)gr * Ntot + gc] = v;
                }
            }
        }
    }
}

// ------------- CSR gather aggregation, F=128, float4 lanes -------------------
// SPLIT: write bf16 hi/lo planes (for feeding MFMA GEMM); else fp32 (+bias).
template <bool SPLIT>
__global__ __launch_bounds__(256) void k_aggregate4(const float4* __restrict__ h4,
                                                    const float* __restrict__ dinv,
                                                    const int* __restrict__ rowptr,
                                                    const int* __restrict__ col,
                                                    const float* __restrict__ val,
                                                    const float* __restrict__ bias,
                                                    float4* __restrict__ out4,
                                                    u16* __restrict__ outh,
                                                    u16* __restrict__ outl, int N) {
    int node = blockIdx.x * 8 + (threadIdx.x >> 5);
    int lane = threadIdx.x & 31;
    if (node >= N) return;
    float di = dinv[node];
    float s = di * di;
    float4 self = h4[(size_t)node * 32 + lane];
    float4 acc;
    acc.x = self.x * s; acc.y = self.y * s; acc.z = self.z * s; acc.w = self.w * s;
    if (!SPLIT && bias) {
        float4 b = reinterpret_cast<const float4*>(bias)[lane];
        acc.x += b.x; acc.y += b.y; acc.z += b.z; acc.w += b.w;
    }
    int p0 = rowptr[node], p1 = rowptr[node + 1];
    int p = p0;
    for (; p + 4 <= p1; p += 4) {
        int c0 = col[p], c1 = col[p + 1], c2 = col[p + 2], c3 = col[p + 3];
        float v0 = val[p], v1 = val[p + 1], v2 = val[p + 2], v3 = val[p + 3];
        float4 g0 = h4[(size_t)c0 * 32 + lane];
        float4 g1 = h4[(size_t)c1 * 32 + lane];
        float4 g2 = h4[(size_t)c2 * 32 + lane];
        float4 g3 = h4[(size_t)c3 * 32 + lane];
        acc.x = fmaf(g0.x, v0, acc.x); acc.y = fmaf(g0.y, v0, acc.y);
        acc.z = fmaf(g0.z, v0, acc.z); acc.w = fmaf(g0.w, v0, acc.w);
        acc.x = fmaf(g1.x, v1, acc.x); acc.y = fmaf(g1.y, v1, acc.y);
        acc.z = fmaf(g1.z, v1, acc.z); acc.w = fmaf(g1.w, v1, acc.w);
        acc.x = fmaf(g2.x, v2, acc.x); acc.y = fmaf(g2.y, v2, acc.y);
        acc.z = fmaf(g2.z, v2, acc.z); acc.w = fmaf(g2.w, v2, acc.w);
        acc.x = fmaf(g3.x, v3, acc.x); acc.y = fmaf(g3.y, v3, acc.y);
        acc.z = fmaf(g3.z, v3, acc.z); acc.w = fmaf(g3.w, v3, acc.w);
    }
    for (; p < p1; ++p) {
        int c = col[p];
        float v = val[p];
        float4 g = h4[(size_t)c * 32 + lane];
        acc.x = fmaf(g.x, v, acc.x); acc.y = fmaf(g.y, v, acc.y);
        acc.z = fmaf(g.z, v, acc.z); acc.w = fmaf(g.w, v, acc.w);
    }
    if (SPLIT) {
        ushort4 hv, lv;
        bsplit(acc.x, hv.x, lv.x);
        bsplit(acc.y, hv.y, lv.y);
        bsplit(acc.z, hv.z, lv.z);
        bsplit(acc.w, hv.w, lv.w);
        reinterpret_cast<ushort4*>(outh)[(size_t)node * 32 + lane] = hv;
        reinterpret_cast<ushort4*>(outl)[(size_t)node * 32 + lane] = lv;
    } else {
        out4[(size_t)node * 32 + lane] = acc;
    }
}

// ---------------- launch ----------------
extern "C" void kernel_launch(void* const* d_in, const int* in_sizes, int n_in,
                              void* d_out, int out_size, void* d_ws, size_t ws_size,
                              hipStream_t stream) {
    (void)n_in; (void)out_size; (void)ws_size;
    const float* x  = (const float*)d_in[0];
    const int*   ei = (const int*)d_in[1];
    const float* w  = (const float*)d_in[2];
    const float* W1 = (const float*)d_in[3];
    const float* b1 = (const float*)d_in[4];
    const float* W2 = (const float*)d_in[5];
    const float* b2 = (const float*)d_in[6];
    float* out = (float*)d_out;

    int N = in_sizes[0] / INCH;  // 50000
    int E = in_sizes[1] / 2;     // 800000
    const int* src = ei;
    const int* dst = ei + E;

    char* ws = (char*)d_ws;
    size_t off = 0;
    auto alloc = [&](size_t bytes) -> char* {
        size_t p = (off + 255) & ~(size_t)255;
        off = p + bytes;
        return ws + p;
    };
    float* dinv   = (float*)alloc((size_t)N * 4);
    int*   cnt    = (int*)  alloc((size_t)N * 4);
    int*   rowptr = (int*)  alloc((size_t)(N + 1) * 4);
    int*   bsum   = (int*)  alloc(1024);
    int*   col    = (int*)  alloc((size_t)E * 4);
    float* val    = (float*)alloc((size_t)E * 4);
    u16*   axh    = (u16*)  alloc((size_t)N * INCH * 2);   // A@x hi   (N x 128)
    u16*   axl    = (u16*)  alloc((size_t)N * INCH * 2);   // A@x lo
    u16*   hdh    = (u16*)  alloc((size_t)N * NHID * 2);   // dropout(relu) hi (N x 256)
    u16*   hdl    = (u16*)  alloc((size_t)N * NHID * 2);
    u16*   w1h    = (u16*)  alloc((size_t)INCH * NHID * 2);
    u16*   w1l    = (u16*)  alloc((size_t)INCH * NHID * 2);
    u16*   w2h    = (u16*)  alloc((size_t)NHID * OUTCH * 2);
    u16*   w2l    = (u16*)  alloc((size_t)NHID * OUTCH * 2);
    // g2 aliases the dead ax planes (axh+axl contiguous 25.6 MB >= N*128*4)
    float* g2     = (float*)axh;

    int nb = (N + 255) / 256;
    int eb = (E + 255) / 256;

    k_init<<<nb, 256, 0, stream>>>(dinv, cnt, N);
    k_edge_deg_hist<<<eb, 256, 0, stream>>>(dst, w, dinv, cnt, E);
    k_dinv<<<nb, 256, 0, stream>>>(dinv, N);
    scan_block<<<nb, 256, 0, stream>>>(cnt, rowptr, bsum, N);
    scan_partials<<<1, 256, 0, stream>>>(bsum, nb);
    scan_add<<<nb, 256, 0, stream>>>(rowptr, cnt, bsum, N, E);
    k_place<<<eb, 256, 0, stream>>>(src, dst, w, dinv, cnt, col, val, E);
    conv_wt<<<(INCH * NHID + 255) / 256, 256, 0, stream>>>(W1, w1h, w1l, INCH, NHID);
    conv_wt<<<(NHID * OUTCH + 255) / 256, 256, 0, stream>>>(W2, w2h, w2l, NHID, OUTCH);

    int ab = (N + 7) / 8;

    // layer 1: ax = A @ x (split planes); hd = dropout(relu(ax @ W1 + b1)) (split)
    k_aggregate4<true><<<ab, 256, 0, stream>>>((const float4*)x, dinv, rowptr, col, val,
                                               nullptr, nullptr, axh, axl, N);
    dim3 gg1(NHID / 128, (N + 127) / 128);
    gemm_mfma<128, 64, true><<<gg1, 256, 0, stream>>>(axh, axl, w1h, w1l, b1,
                                                      hdh, hdl, nullptr, N, NHID, INCH);

    // layer 2: g2 = hd @ W2 (fp32); out = A @ g2 + b2
    dim3 gg2(OUTCH / 64, (N + 127) / 128);
    gemm_mfma<64, 32, false><<<gg2, 256, 0, stream>>>(hdh, hdl, w2h, w2l, nullptr,
                                                      nullptr, nullptr, g2, N, OUTCH, NHID);
    k_aggregate4<false><<<ab, 256, 0, stream>>>((const float4*)g2, dinv, rowptr, col, val,
                                                b2, (float4*)out, nullptr, nullptr, N);
}

// Round 5
// 376.959 us; speedup vs baseline: 1.2538x; 1.1202x over previous
//
#include <hip/hip_runtime.h>
#include <hip/hip_bf16.h>
#include <cstdint>

#define INCH 128
#define NHID 256
#define OUTCH 128

typedef unsigned short u16;
typedef unsigned long long u64;
typedef __attribute__((ext_vector_type(8))) short s8v;   // 8 bf16 (4 VGPRs)
typedef __attribute__((ext_vector_type(4))) float f4v;   // 4 fp32 acc

// ---------------- bf16 hi/lo split (Markidis) ----------------
__device__ __forceinline__ void bsplit(float a, u16& hi, u16& lo) {
    unsigned u = __float_as_uint(a);
    unsigned r = (u + 0x7fffu + ((u >> 16) & 1u)) >> 16;   // RTN-even bf16
    hi = (u16)r;
    float res = a - __uint_as_float(r << 16);
    unsigned u2 = __float_as_uint(res);
    lo = (u16)((u2 + 0x7fffu + ((u2 >> 16) & 1u)) >> 16);
}

// ---------------- threefry2x32 (JAX-compatible) ----------------
__device__ __forceinline__ unsigned rotl32(unsigned x, int d) {
    return (x << d) | (x >> (32 - d));
}

__device__ __forceinline__ void threefry2x32(unsigned k0, unsigned k1,
                                             unsigned x0, unsigned x1,
                                             unsigned& o0, unsigned& o1) {
    unsigned ks2 = k0 ^ k1 ^ 0x1BD11BDAu;
#define TF_R(r) { x0 += x1; x1 = rotl32(x1, (r)); x1 ^= x0; }
    x0 += k0; x1 += k1;
    TF_R(13) TF_R(15) TF_R(26) TF_R(6)
    x0 += k1; x1 += ks2 + 1u;
    TF_R(17) TF_R(29) TF_R(16) TF_R(24)
    x0 += ks2; x1 += k0 + 2u;
    TF_R(13) TF_R(15) TF_R(26) TF_R(6)
    x0 += k0; x1 += k1 + 3u;
    TF_R(17) TF_R(29) TF_R(16) TF_R(24)
    x0 += k1; x1 += ks2 + 4u;
    TF_R(13) TF_R(15) TF_R(26) TF_R(6)
    x0 += ks2; x1 += k0 + 5u;
#undef TF_R
    o0 = x0; o1 = x1;
}

__device__ __forceinline__ bool dropout_keep(unsigned j) {
    unsigned o0, o1;
    threefry2x32(0u, 42u, 0u, j, o0, o1);
    return ((o0 ^ o1) & 0x80000000u) == 0u;
}

// ---------------- graph preprocessing ----------------
// packed[d]: low 32 = sum(w) in 8.24 fixed point, high 32 = edge count.
__global__ void k_init(u64* packed, int N) {
    int i = blockIdx.x * blockDim.x + threadIdx.x;
    if (i < N) packed[i] = 0ull;
}

__global__ void k_hist64(const int4* __restrict__ dst4, const float4* __restrict__ w4,
                         u64* packed, int E4) {
    int i = blockIdx.x * blockDim.x + threadIdx.x;
    if (i < E4) {
        int4 d = dst4[i];
        float4 ww = w4[i];
        const u64 one = 1ull << 32;
        atomicAdd(&packed[d.x], one | (u64)__float2uint_rn(ww.x * 16777216.0f));
        atomicAdd(&packed[d.y], one | (u64)__float2uint_rn(ww.y * 16777216.0f));
        atomicAdd(&packed[d.z], one | (u64)__float2uint_rn(ww.z * 16777216.0f));
        atomicAdd(&packed[d.w], one | (u64)__float2uint_rn(ww.w * 16777216.0f));
    }
}

// decode: deg = 1 (self-loop) + fixsum * 2^-24; dinv = rsqrt(deg); cnt = high word
__global__ void k_dinv_cnt(const u64* __restrict__ packed, float* __restrict__ dinv,
                           int* __restrict__ cnt, int N) {
    int i = blockIdx.x * blockDim.x + threadIdx.x;
    if (i < N) {
        u64 p = packed[i];
        float deg = 1.0f + (float)(unsigned)(p & 0xffffffffull) * (1.0f / 16777216.0f);
        dinv[i] = rsqrtf(deg);          // deg >= 1 always
        cnt[i] = (int)(p >> 32);
    }
}

__global__ void scan_block(const int* __restrict__ cnt, int* __restrict__ rowptr,
                           int* __restrict__ bsum, int N) {
    __shared__ int s[256];
    int t = threadIdx.x;
    int i = blockIdx.x * 256 + t;
    int v = (i < N) ? cnt[i] : 0;
    s[t] = v;
    __syncthreads();
    for (int off = 1; off < 256; off <<= 1) {
        int tv = (t >= off) ? s[t - off] : 0;
        __syncthreads();
        s[t] += tv;
        __syncthreads();
    }
    if (i < N) rowptr[i] = s[t] - v;
    if (t == 255) bsum[blockIdx.x] = s[255];
}

__global__ void scan_partials(int* bsum, int nb) {
    __shared__ int s[256];
    int t = threadIdx.x;
    int v = (t < nb) ? bsum[t] : 0;
    s[t] = v;
    __syncthreads();
    for (int off = 1; off < 256; off <<= 1) {
        int tv = (t >= off) ? s[t - off] : 0;
        __syncthreads();
        s[t] += tv;
        __syncthreads();
    }
    if (t < nb) bsum[t] = s[t] - v;
}

__global__ void scan_add(int* rowptr, int* cursor, const int* __restrict__ bsum,
                         int N, int E) {
    int i = blockIdx.x * 256 + threadIdx.x;
    if (i < N) {
        int r = rowptr[i] + bsum[blockIdx.x];
        rowptr[i] = r;
        cursor[i] = r;
    }
    if (i == N) rowptr[N] = E;
}

// place {src, norm} as one int2 per edge (single 32B sector per scatter)
__global__ void k_place(const int* __restrict__ src, const int* __restrict__ dst,
                        const float* __restrict__ w, const float* __restrict__ dinv,
                        int* cursor, int2* __restrict__ cv, int E) {
    int e = blockIdx.x * blockDim.x + threadIdx.x;
    if (e < E) {
        int s = src[e], d = dst[e];
        float nrm = dinv[s] * w[e] * dinv[d];
        int pos = atomicAdd(&cursor[d], 1);
        cv[pos] = make_int2(s, __float_as_int(nrm));
    }
}

// --------- weight transpose + split: W[K][N] fp32 -> Wh/Wl[N][K] bf16 bits -----
__global__ void conv_wt(const float* __restrict__ W, u16* __restrict__ Wh,
                        u16* __restrict__ Wl, int K, int N) {
    int i = blockIdx.x * 256 + threadIdx.x;
    if (i >= K * N) return;
    int k = i / N, n = i % N;
    u16 hi, lo;
    bsplit(W[i], hi, lo);
    Wh[(size_t)n * K + k] = hi;
    Wl[(size_t)n * K + k] = lo;
}

// ---------------- MFMA split-bf16 GEMM ----------------
// C[M,Ntot] = A[M,K] @ B^T[Ntot,K], A/B given as bf16 hi/lo planes.
// BM=128 rows, BN cols per block; 4 waves as 2x2 of (64 x WN) wave tiles.
// mfma_f32_16x16x32_bf16: A/B-frag lane l: (m|n)=l&15, k=(l>>4)*8+i;
// D: col=l&15, row=(l>>4)*4+reg  [m89/m91 verified].
// ACT: C = dropout(relu(C + bias)) -> hi/lo planes; else fp32 out (no bias).
template <int BN, int WN, bool ACT>
__global__ __launch_bounds__(256) void gemm_mfma(
    const u16* __restrict__ Ah, const u16* __restrict__ Al,
    const u16* __restrict__ Bh, const u16* __restrict__ Bl,
    const float* __restrict__ bias,
    u16* __restrict__ Ch, u16* __restrict__ Cl, float* __restrict__ Cf,
    int M, int Ntot, int K) {
    constexpr int BM = 128;
    constexpr int MFRAG = 4;
    constexpr int NFRAG = WN / 16;
    // rows padded to 40 u16 (80 B = 20-bank stride -> 2-way aliasing, free)
    __shared__ u16 Alh[BM][40], All[BM][40];
    __shared__ u16 Blh[BN][40], Bll[BN][40];

    const int tid = threadIdx.x;
    const int lane = tid & 63;
    const int w = tid >> 6;
    const int wm = (w >> 1) * 64;
    const int wn = (w & 1) * WN;
    const int l15 = lane & 15;
    const int kh = lane >> 4;            // 0..3
    const int row0 = blockIdx.y * BM;
    const int col0 = blockIdx.x * BN;

    f4v acc[MFRAG][NFRAG];
#pragma unroll
    for (int f = 0; f < MFRAG; ++f)
#pragma unroll
        for (int g = 0; g < NFRAG; ++g) acc[f][g] = (f4v){0.f, 0.f, 0.f, 0.f};

    for (int k0 = 0; k0 < K; k0 += 32) {
        // stage A tile: 128 rows x 32 k, both planes, 16B chunks
#pragma unroll
        for (int c = tid; c < BM * 4; c += 256) {
            int m = c >> 2, ko = (c & 3) * 8;
            int gm = row0 + m;
            uint4 vh = make_uint4(0, 0, 0, 0), vl = make_uint4(0, 0, 0, 0);
            if (gm < M) {
                size_t gi = (size_t)gm * K + k0 + ko;
                vh = *reinterpret_cast<const uint4*>(&Ah[gi]);
                vl = *reinterpret_cast<const uint4*>(&Al[gi]);
            }
            *reinterpret_cast<uint4*>(&Alh[m][ko]) = vh;
            *reinterpret_cast<uint4*>(&All[m][ko]) = vl;
        }
        // stage B tile: BN rows x 32 k
#pragma unroll
        for (int c = tid; c < BN * 4; c += 256) {
            int n = c >> 2, ko = (c & 3) * 8;
            size_t gi = (size_t)(col0 + n) * K + k0 + ko;
            *reinterpret_cast<uint4*>(&Blh[n][ko]) = *reinterpret_cast<const uint4*>(&Bh[gi]);
            *reinterpret_cast<uint4*>(&Bll[n][ko]) = *reinterpret_cast<const uint4*>(&Bl[gi]);
        }
        __syncthreads();

        s8v afh[MFRAG], afl[MFRAG], bfh[NFRAG], bfl[NFRAG];
#pragma unroll
        for (int f = 0; f < MFRAG; ++f) {
            afh[f] = *reinterpret_cast<const s8v*>(&Alh[wm + f * 16 + l15][kh * 8]);
            afl[f] = *reinterpret_cast<const s8v*>(&All[wm + f * 16 + l15][kh * 8]);
        }
#pragma unroll
        for (int g = 0; g < NFRAG; ++g) {
            bfh[g] = *reinterpret_cast<const s8v*>(&Blh[wn + g * 16 + l15][kh * 8]);
            bfl[g] = *reinterpret_cast<const s8v*>(&Bll[wn + g * 16 + l15][kh * 8]);
        }
#pragma unroll
        for (int f = 0; f < MFRAG; ++f)
#pragma unroll
            for (int g = 0; g < NFRAG; ++g) {
                acc[f][g] = __builtin_amdgcn_mfma_f32_16x16x32_bf16(afl[f], bfh[g], acc[f][g], 0, 0, 0);
                acc[f][g] = __builtin_amdgcn_mfma_f32_16x16x32_bf16(afh[f], bfl[g], acc[f][g], 0, 0, 0);
                acc[f][g] = __builtin_amdgcn_mfma_f32_16x16x32_bf16(afh[f], bfh[g], acc[f][g], 0, 0, 0);
            }
        __syncthreads();
    }

    // epilogue
#pragma unroll
    for (int f = 0; f < MFRAG; ++f) {
#pragma unroll
        for (int g = 0; g < NFRAG; ++g) {
#pragma unroll
            for (int r = 0; r < 4; ++r) {
                int gr = row0 + wm + f * 16 + kh * 4 + r;
                if (gr >= M) continue;
                int gc = col0 + wn + g * 16 + l15;
                float v = acc[f][g][r];
                if (ACT) {
                    v = fmaxf(v + bias[gc], 0.f);
                    unsigned j = (unsigned)gr * (unsigned)Ntot + (unsigned)gc;
                    v = dropout_keep(j) ? v * 2.f : 0.f;
                    u16 hi, lo;
                    bsplit(v, hi, lo);
                    Ch[(size_t)gr * Ntot + gc] = hi;
                    Cl[(size_t)gr * Ntot + gc] = lo;
                } else {
                    Cf[(size_t)gr * Ntot + gc] = v;
                }
            }
        }
    }
}

// ------------- CSR gather aggregation, F=128, float4 lanes, unroll 8 ---------
// SPLIT: write bf16 hi/lo planes (for feeding MFMA GEMM); else fp32 (+bias).
template <bool SPLIT>
__global__ __launch_bounds__(256) void k_aggregate4(const float4* __restrict__ h4,
                                                    const float* __restrict__ dinv,
                                                    const int* __restrict__ rowptr,
                                                    const int2* __restrict__ cv,
                                                    const float* __restrict__ bias,
                                                    float4* __restrict__ out4,
                                                    u16* __restrict__ outh,
                                                    u16* __restrict__ outl, int N) {
    int node = blockIdx.x * 8 + (threadIdx.x >> 5);
    int lane = threadIdx.x & 31;
    if (node >= N) return;
    float di = dinv[node];
    float s = di * di;
    float4 self = h4[(size_t)node * 32 + lane];
    float4 acc;
    acc.x = self.x * s; acc.y = self.y * s; acc.z = self.z * s; acc.w = self.w * s;
    if (!SPLIT && bias) {
        float4 b = reinterpret_cast<const float4*>(bias)[lane];
        acc.x += b.x; acc.y += b.y; acc.z += b.z; acc.w += b.w;
    }
    int p0 = rowptr[node], p1 = rowptr[node + 1];
    int p = p0;
    for (; p + 8 <= p1; p += 8) {
        int2 e0 = cv[p + 0], e1 = cv[p + 1], e2 = cv[p + 2], e3 = cv[p + 3];
        int2 e4 = cv[p + 4], e5 = cv[p + 5], e6 = cv[p + 6], e7 = cv[p + 7];
        float4 g0 = h4[(size_t)e0.x * 32 + lane];
        float4 g1 = h4[(size_t)e1.x * 32 + lane];
        float4 g2 = h4[(size_t)e2.x * 32 + lane];
        float4 g3 = h4[(size_t)e3.x * 32 + lane];
        float4 g4 = h4[(size_t)e4.x * 32 + lane];
        float4 g5 = h4[(size_t)e5.x * 32 + lane];
        float4 g6 = h4[(size_t)e6.x * 32 + lane];
        float4 g7 = h4[(size_t)e7.x * 32 + lane];
#define ACC(gv, ev) { float v = __int_as_float(ev.y); \
        acc.x = fmaf(gv.x, v, acc.x); acc.y = fmaf(gv.y, v, acc.y); \
        acc.z = fmaf(gv.z, v, acc.z); acc.w = fmaf(gv.w, v, acc.w); }
        ACC(g0, e0) ACC(g1, e1) ACC(g2, e2) ACC(g3, e3)
        ACC(g4, e4) ACC(g5, e5) ACC(g6, e6) ACC(g7, e7)
    }
    for (; p < p1; ++p) {
        int2 e = cv[p];
        float4 g = h4[(size_t)e.x * 32 + lane];
        ACC(g, e)
    }
#undef ACC
    if (SPLIT) {
        ushort4 hv, lv;
        bsplit(acc.x, hv.x, lv.x);
        bsplit(acc.y, hv.y, lv.y);
        bsplit(acc.z, hv.z, lv.z);
        bsplit(acc.w, hv.w, lv.w);
        reinterpret_cast<ushort4*>(outh)[(size_t)node * 32 + lane] = hv;
        reinterpret_cast<ushort4*>(outl)[(size_t)node * 32 + lane] = lv;
    } else {
        out4[(size_t)node * 32 + lane] = acc;
    }
}

// ---------------- launch ----------------
extern "C" void kernel_launch(void* const* d_in, const int* in_sizes, int n_in,
                              void* d_out, int out_size, void* d_ws, size_t ws_size,
                              hipStream_t stream) {
    (void)n_in; (void)out_size; (void)ws_size;
    const float* x  = (const float*)d_in[0];
    const int*   ei = (const int*)d_in[1];
    const float* w  = (const float*)d_in[2];
    const float* W1 = (const float*)d_in[3];
    const float* b1 = (const float*)d_in[4];
    const float* W2 = (const float*)d_in[5];
    const float* b2 = (const float*)d_in[6];
    float* out = (float*)d_out;

    int N = in_sizes[0] / INCH;  // 50000
    int E = in_sizes[1] / 2;     // 800000
    const int* src = ei;
    const int* dst = ei + E;

    char* ws = (char*)d_ws;
    size_t off = 0;
    auto alloc = [&](size_t bytes) -> char* {
        size_t p = (off + 255) & ~(size_t)255;
        off = p + bytes;
        return ws + p;
    };
    u64*   packed = (u64*)  alloc((size_t)N * 8);
    float* dinv   = (float*)alloc((size_t)N * 4);
    int*   cnt    = (int*)  alloc((size_t)N * 4);          // histogram, then cursor
    int*   rowptr = (int*)  alloc((size_t)(N + 1) * 4);
    int*   bsum   = (int*)  alloc(1024);
    int2*  cv     = (int2*) alloc((size_t)E * 8);          // {col, val} packed
    u16*   axh    = (u16*)  alloc((size_t)N * INCH * 2);   // A@x hi   (N x 128)
    u16*   axl    = (u16*)  alloc((size_t)N * INCH * 2);   // A@x lo
    u16*   hdh    = (u16*)  alloc((size_t)N * NHID * 2);   // dropout(relu) hi (N x 256)
    u16*   hdl    = (u16*)  alloc((size_t)N * NHID * 2);
    u16*   w1h    = (u16*)  alloc((size_t)INCH * NHID * 2);
    u16*   w1l    = (u16*)  alloc((size_t)INCH * NHID * 2);
    u16*   w2h    = (u16*)  alloc((size_t)NHID * OUTCH * 2);
    u16*   w2l    = (u16*)  alloc((size_t)NHID * OUTCH * 2);
    // g2 aliases the dead ax planes (axh+axl contiguous 25.6 MB >= N*128*4)
    float* g2     = (float*)axh;

    int nb = (N + 255) / 256;
    int eb = (E + 255) / 256;
    int eb4 = (E / 4 + 255) / 256;

    k_init<<<nb, 256, 0, stream>>>(packed, N);
    k_hist64<<<eb4, 256, 0, stream>>>((const int4*)dst, (const float4*)w, packed, E / 4);
    k_dinv_cnt<<<nb, 256, 0, stream>>>(packed, dinv, cnt, N);
    scan_block<<<nb, 256, 0, stream>>>(cnt, rowptr, bsum, N);
    scan_partials<<<1, 256, 0, stream>>>(bsum, nb);
    scan_add<<<nb, 256, 0, stream>>>(rowptr, cnt, bsum, N, E);
    k_place<<<eb, 256, 0, stream>>>(src, dst, w, dinv, cnt, cv, E);
    conv_wt<<<(INCH * NHID + 255) / 256, 256, 0, stream>>>(W1, w1h, w1l, INCH, NHID);
    conv_wt<<<(NHID * OUTCH + 255) / 256, 256, 0, stream>>>(W2, w2h, w2l, NHID, OUTCH);

    int ab = (N + 7) / 8;

    // layer 1: ax = A @ x (split planes); hd = dropout(relu(ax @ W1 + b1)) (split)
    k_aggregate4<true><<<ab, 256, 0, stream>>>((const float4*)x, dinv, rowptr, cv,
                                               nullptr, nullptr, axh, axl, N);
    dim3 gg1(NHID / 128, (N + 127) / 128);
    gemm_mfma<128, 64, true><<<gg1, 256, 0, stream>>>(axh, axl, w1h, w1l, b1,
                                                      hdh, hdl, nullptr, N, NHID, INCH);

    // layer 2: g2 = hd @ W2 (fp32); out = A @ g2 + b2
    dim3 gg2(OUTCH / 64, (N + 127) / 128);
    gemm_mfma<64, 32, false><<<gg2, 256, 0, stream>>>(hdh, hdl, w2h, w2l, nullptr,
                                                      nullptr, nullptr, g2, N, OUTCH, NHID);
    k_aggregate4<false><<<ab, 256, 0, stream>>>((const float4*)g2, dinv, rowptr, cv,
                                                b2, (float4*)out, nullptr, nullptr, N);
}